// Round 9
// baseline (31.069 us; speedup 1.0000x reference)
//
#include <hip/hip_runtime.h>

namespace {

struct c32 { float x, y; };

typedef unsigned short u16x8 __attribute__((ext_vector_type(8)));

__device__ __forceinline__ c32 cmul(c32 a, c32 b) {
    c32 r;
    r.x = fmaf(a.x, b.x, -a.y * b.y);
    r.y = fmaf(a.x, b.y,  a.y * b.x);
    return r;
}

// float -> bf16 with round-to-nearest-even (finite inputs only)
__device__ __forceinline__ unsigned short f2bf(float f) {
    union { float f; unsigned u; } v; v.f = f;
    unsigned r = v.u + 0x7FFF + ((v.u >> 16) & 1);
    return (unsigned short)(r >> 16);
}

constexpr int NQ   = 10;
constexpr int DIM  = 1024;   // 2^10
constexpr int HDIM = 32;     // 2^5
constexpr int ROWS_PER_BLOCK = 32;
constexpr int THREADS = 256;

__global__ __launch_bounds__(THREADS)
void r3_kron_kernel(const float* __restrict__ angles, unsigned short* __restrict__ out) {
    __shared__ c32 mats[NQ][2][2];
    __shared__ c32 As[HDIM * HDIM];   // kron of qubits 0..4  (32x32)
    __shared__ c32 Bs[HDIM * HDIM];   // kron of qubits 5..9  (32x32)

    const int tid  = threadIdx.x;
    const int b    = blockIdx.x >> 5;          // 32 blocks per batch
    const int ih   = blockIdx.x & 31;          // rows ih*32 .. ih*32+31

    // --- ten 2x2 matrices from angles ---
    if (tid < NQ) {
        const float* ang = angles + (b * NQ + tid) * 3;
        const float omega = ang[0], theta = ang[1], phi = ang[2];
        float st, ct, s1, c1, s2, c2;
        sincosf(0.5f * theta,           &st, &ct);
        sincosf(0.5f * (phi + omega),   &s1, &c1);
        sincosf(0.5f * (phi - omega),   &s2, &c2);
        // m11 = e^{-i(phi+omega)/2} c ; m12 = -e^{ i(phi-omega)/2} s
        // m21 = e^{-i(phi-omega)/2} s ; m22 =  e^{ i(phi+omega)/2} c
        mats[tid][0][0] = {  ct * c1, -ct * s1 };
        mats[tid][0][1] = { -st * c2, -st * s2 };
        mats[tid][1][0] = {  st * c2, -st * s2 };
        mats[tid][1][1] = {  ct * c1,  ct * s1 };
    }
    __syncthreads();

    // --- build half-krons A (qubits 0..4) and B (qubits 5..9) in LDS ---
    for (int idx = tid; idx < HDIM * HDIM; idx += THREADS) {
        const int r = idx >> 5, c = idx & 31;   // 5-bit row/col
        c32 pa = mats[0][(r >> 4) & 1][(c >> 4) & 1];
        c32 pb = mats[5][(r >> 4) & 1][(c >> 4) & 1];
#pragma unroll
        for (int q = 1; q < 5; ++q) {
            const int s = 4 - q;   // qubit q sits at bit (4-q)
            pa = cmul(pa, mats[q    ][(r >> s) & 1][(c >> s) & 1]);
            pb = cmul(pb, mats[5 + q][(r >> s) & 1][(c >> s) & 1]);
        }
        As[idx] = pa;
        Bs[idx] = pb;
    }
    __syncthreads();

    // --- stream output rows: out[i,j] = A[ih, j>>5] * B[i&31, j&31] ---
    // Verified layout (round-8 probe): row-major (B,D,D), q0 at MSB, each
    // complex element stored as the bf16 pair (IM, RE).
    const c32 a  = As[ih * HDIM + (tid >> 3)];  // jh = t>>3, constant per thread
    const int jl = (4 * tid) & 31;              // low 5 bits of column

    for (int r = 0; r < ROWS_PER_BLOCK; ++r) {
        const int i = ih * ROWS_PER_BLOCK + r;  // global row; il = r
        const c32 b0 = Bs[r * HDIM + jl + 0];
        const c32 b1 = Bs[r * HDIM + jl + 1];
        const c32 b2 = Bs[r * HDIM + jl + 2];
        const c32 b3 = Bs[r * HDIM + jl + 3];
        const c32 c0 = cmul(a, b0), c1 = cmul(a, b1);
        const c32 c2 = cmul(a, b2), c3 = cmul(a, b3);
        u16x8 v;
        v[0] = f2bf(c0.y); v[1] = f2bf(c0.x);   // (im, re) per element
        v[2] = f2bf(c1.y); v[3] = f2bf(c1.x);
        v[4] = f2bf(c2.y); v[5] = f2bf(c2.x);
        v[6] = f2bf(c3.y); v[7] = f2bf(c3.x);
        // row base in u16x8 units: (b*1024 + i) * 2048 bf16 / 8 = (b*1024+i)*256
        u16x8* dst = reinterpret_cast<u16x8*>(out) + ((size_t)(b * DIM + i) * (DIM * 2 / 8)) + tid;
        __builtin_nontemporal_store(v, dst);
    }
}

} // namespace

extern "C" void kernel_launch(void* const* d_in, const int* in_sizes, int n_in,
                              void* d_out, int out_size, void* d_ws, size_t ws_size,
                              hipStream_t stream) {
    const float* angles = (const float*)d_in[0];
    unsigned short* out = (unsigned short*)d_out;
    const int B = in_sizes[0] / (NQ * 3);               // 32
    const dim3 grid(B * (DIM / ROWS_PER_BLOCK));        // 32 * 32 = 1024 blocks
    r3_kron_kernel<<<grid, THREADS, 0, stream>>>(angles, out);
}